// Round 9
// baseline (96.568 us; speedup 1.0000x reference)
//
#include <hip/hip_runtime.h>
#include <hip/hip_bf16.h>

// GAT MultiHeads, MI355X. N=4096, F_IN=256, H=8, D=16, HD=128.
// All inputs/outputs f32; attention inner loop packed f16, masks via LDS f16.
//
// Math identities (vs reference):
//  - logits[h,i,j] = f1[h,j] + f2[h,i]  (rank-1, never materialized)
//  - exp(lrelu(x)) = max(e^x, e^{0.3x})  (exp monotone, lrelu = max(x,0.3x))
//    => q = max(E1[j]*A[i], E3[j]*B[i]); E1=e^f1, E3=e^{0.3f1}, A=e^f2, B=e^{0.3f2}
//  - no max-subtraction: logits bounded (|x| < ~2), softmax ratio invariant
//  - g in {0,1} => exact in f16; mask applied as packed-f16 multiply
//  - denominators = P @ ones via MFMA (idle pipe), lane gets its row sum
//  - fully-masked rows: denom clamp 1e-30 => output row 0 (matches densify)
//
// k_prep (cvt) / k_score (score GEMM + f16 exp tables) /
// k_attn (j-split x4; per 512-col half-window: stage f32 masks -> f16 LDS,
//         then 16 MFMA iters; no scalar-path loads) /
// k_reduce (sum partials + output GEMM).

#define NN 4096
#define LOG2E 1.44269504088896340736f
#define NS 4          // j-split chunks
#define CHUNK 1024    // NN/NS
#define WHALF 512     // LDS mask half-window

typedef short bf16x8 __attribute__((ext_vector_type(8)));
typedef float f32x4  __attribute__((ext_vector_type(4)));
typedef _Float16 h16x8 __attribute__((ext_vector_type(8)));
typedef __fp16  fp16x2 __attribute__((ext_vector_type(2)));

__device__ __forceinline__ unsigned short f2bf_rn(float f) {
  union { float f; unsigned int i; } v; v.f = f;
  unsigned int r = v.i + 0x7FFFu + ((v.i >> 16) & 1u);  // RTNE
  return (unsigned short)(r >> 16);
}
// two f32 -> packed 2x f16 (RTZ) as u32
__device__ __forceinline__ unsigned int pk2(float lo, float hi) {
  fp16x2 h = __builtin_amdgcn_cvt_pkrtz(lo, hi);
  union { fp16x2 h; unsigned int u; } v; v.h = h; return v.u;
}

// ---- K0: one-time conversions. grid 512x256 ----
__global__ __launch_bounds__(256) void k_prep(
    const float* __restrict__ X, const float* __restrict__ Ww,
    const float* __restrict__ Wcat, const float* __restrict__ proj,
    const float* __restrict__ Wcb, const float* __restrict__ bias,
    const float* __restrict__ prb,
    unsigned short* __restrict__ Xb, unsigned short* __restrict__ WwT,
    unsigned short* __restrict__ WpT, float* __restrict__ bsum)
{
  const int tid = blockIdx.x * 256 + threadIdx.x;  // 0..131071
  {  // X[4096][256] f32 -> bf16 (RTNE), 8 elements/thread
    const float4 a = *(const float4*)(X + (size_t)tid * 8);
    const float4 b = *(const float4*)(X + (size_t)tid * 8 + 4);
    uint4 o;
    o.x = (unsigned)f2bf_rn(a.x) | ((unsigned)f2bf_rn(a.y) << 16);
    o.y = (unsigned)f2bf_rn(a.z) | ((unsigned)f2bf_rn(a.w) << 16);
    o.z = (unsigned)f2bf_rn(b.x) | ((unsigned)f2bf_rn(b.y) << 16);
    o.w = (unsigned)f2bf_rn(b.z) | ((unsigned)f2bf_rn(b.w) << 16);
    *(uint4*)(Xb + (size_t)tid * 8) = o;
  }
  if (tid < 32768) {  // WwT[c][k] = Ww[k][c], bf16
    int c = tid & 127, k = tid >> 7;
    WwT[c * 256 + k] = f2bf_rn(Ww[k * 128 + c]);
  }
  if (tid < 65536) {  // WpT[c][k]: k<256 -> Wcat[k][c], else proj[k-256][c]
    int c = tid & 127, k = tid >> 7;
    float v = (k < 256) ? Wcat[k * 128 + c] : proj[(k - 256) * 128 + c];
    WpT[c * 512 + k] = f2bf_rn(v);
  }
  if (tid < 128) bsum[tid] = Wcb[tid] + bias[tid] + prb[tid];
}

// ---- K1: score GEMM + f2 + f16 exp tables. grid 256 x 512 ----
__global__ __launch_bounds__(512) void k_score(
    const unsigned short* __restrict__ Xb, const unsigned short* __restrict__ WwT,
    const float* __restrict__ Wb, const float* __restrict__ wu,
    const float* __restrict__ wv,
    unsigned short* __restrict__ scT, float* __restrict__ f2,
    unsigned short* __restrict__ E1p, unsigned short* __restrict__ E3p)
{
  const int n0 = blockIdx.x * 16;
  const int h = threadIdx.x >> 6, lane = threadIdx.x & 63;
  const int mr = lane & 15, grp = lane >> 4;
  const unsigned short* ap  = Xb  + (size_t)(n0 + mr) * 256;
  const unsigned short* bpp = WwT + (size_t)(h * 16 + mr) * 256;
  f32x4 acc = {0.f, 0.f, 0.f, 0.f};
  #pragma unroll
  for (int ks = 0; ks < 8; ++ks) {
    bf16x8 a = *(const bf16x8*)(ap  + ks * 32 + grp * 8);
    bf16x8 b = *(const bf16x8*)(bpp + ks * 32 + grp * 8);
    acc = __builtin_amdgcn_mfma_f32_16x16x32_bf16(a, b, acc, 0, 0, 0);
  }
  const float wb = Wb[h * 16 + mr];
  float sc[4];
  #pragma unroll
  for (int r = 0; r < 4; ++r) sc[r] = acc[r] + wb;  // score[n0+grp*4+r][h*16+mr]

  {  // scT[h*16+mr][n0+grp*4 .. +3] f16
    uint2 st;
    st.x = pk2(sc[0], sc[1]);
    st.y = pk2(sc[2], sc[3]);
    *(uint2*)(scT + (size_t)(h * 16 + mr) * NN + n0 + grp * 4) = st;
  }

  const float uw = wu[h * 16 + mr], vw = wv[h * 16 + mr];
  float t1[4], t2[4];
  #pragma unroll
  for (int r = 0; r < 4; ++r) { t1[r] = sc[r] * uw; t2[r] = sc[r] * vw; }
  #pragma unroll
  for (int m = 1; m < 16; m <<= 1) {
    #pragma unroll
    for (int r = 0; r < 4; ++r) {
      t1[r] += __shfl_xor(t1[r], m, 64);
      t2[r] += __shfl_xor(t2[r], m, 64);
    }
  }
  if (mr == 0) {
    *(float4*)(f2 + h * NN + n0 + grp * 4) = make_float4(t2[0], t2[1], t2[2], t2[3]);
    float e1[4], e3[4];
    #pragma unroll
    for (int r = 0; r < 4; ++r) {
      e1[r] = __builtin_amdgcn_exp2f(t1[r] * LOG2E);
      e3[r] = __builtin_amdgcn_exp2f(0.3f * t1[r] * LOG2E);
    }
    uint2 p1, p3;
    p1.x = pk2(e1[0], e1[1]);
    p1.y = pk2(e1[2], e1[3]);
    p3.x = pk2(e3[0], e3[1]);
    p3.y = pk2(e3[2], e3[3]);
    *(uint2*)(E1p + h * NN + n0 + grp * 4) = p1;
    *(uint2*)(E3p + h * NN + n0 + grp * 4) = p3;
  }
}

// ---- K2: dual-graph masked softmax attention, j-split x NS ----
// grid = NS*256 (bx = chunk*256 + tile), 512 thr (8 waves = 8 heads).
// Per 512-col half-window: cooperative stage of f32 masks -> f16 LDS
// (read once chip-wide, the HBM floor), then 16 MFMA iters with ds_read
// masks applied via v_pk_mul_f16. No scalar-memory loads in the loop.
__global__ __launch_bounds__(512, 8) void k_attn(
    const float* __restrict__ Dg, const float* __restrict__ Sg,
    const unsigned short* __restrict__ scT, const unsigned short* __restrict__ E1p,
    const unsigned short* __restrict__ E3p, const float* __restrict__ f2,
    float* __restrict__ pn, float* __restrict__ pd)
{
  __shared__ _Float16 mlds[2][16][WHALF + 8];  // [graph][i-row][j + pad]
  const int bx = blockIdx.x;
  const int c = bx >> 8, t = bx & 255;
  const int i0 = t << 4, j0 = c * CHUNK;
  const int tid = threadIdx.x;
  const int h = tid >> 6, lane = tid & 63;
  const int mr = lane & 15, grp = lane >> 4;

  const float f2v = f2[h * NN + i0 + mr];
  const _Float16 afh = (_Float16)__builtin_amdgcn_exp2f(f2v * LOG2E);
  const _Float16 bfh = (_Float16)__builtin_amdgcn_exp2f(0.3f * f2v * LOG2E);
  const h16x8 af8 = {afh, afh, afh, afh, afh, afh, afh, afh};
  const h16x8 bf8 = {bfh, bfh, bfh, bfh, bfh, bfh, bfh, bfh};
  const _Float16 one = (_Float16)1.f;
  const h16x8 ones = {one, one, one, one, one, one, one, one};

  const _Float16* e1p_ = (const _Float16*)E1p + h * NN + j0 + grp * 8;
  const _Float16* e3p_ = (const _Float16*)E3p + h * NN + j0 + grp * 8;
  const _Float16* scp_ = (const _Float16*)scT + (size_t)(h * 16 + mr) * NN + j0 + grp * 8;

  // mask staging role: graph fg, row fr, 32-col segment fs
  const int fg = tid >> 8;
  const int fr = (tid >> 4) & 15;
  const int fs = tid & 15;
  const float* fsrc = (fg ? Sg : Dg) + (size_t)(i0 + fr) * NN + j0 + fs * 32;
  _Float16* fdst = &mlds[fg][fr][fs * 32];

  f32x4 accD = {0.f,0.f,0.f,0.f}, accS = {0.f,0.f,0.f,0.f};
  f32x4 dnD  = {0.f,0.f,0.f,0.f}, dnS  = {0.f,0.f,0.f,0.f};

  for (int w = 0; w < CHUNK / WHALF; ++w) {
    if (w) __syncthreads();  // previous window fully consumed
    {  // stage 32 f32 -> 32 f16 per thread (two groups of 16)
      const float* p = fsrc + w * WHALF;
      #pragma unroll
      for (int q8 = 0; q8 < 2; ++q8) {
        const float4 v0 = *(const float4*)(p + q8 * 16);
        const float4 v1 = *(const float4*)(p + q8 * 16 + 4);
        const float4 v2 = *(const float4*)(p + q8 * 16 + 8);
        const float4 v3 = *(const float4*)(p + q8 * 16 + 12);
        uint4 o0, o1;
        o0.x = pk2(v0.x, v0.y); o0.y = pk2(v0.z, v0.w);
        o0.z = pk2(v1.x, v1.y); o0.w = pk2(v1.z, v1.w);
        o1.x = pk2(v2.x, v2.y); o1.y = pk2(v2.z, v2.w);
        o1.z = pk2(v3.x, v3.y); o1.w = pk2(v3.z, v3.w);
        *(uint4*)(fdst + q8 * 16)     = o0;
        *(uint4*)(fdst + q8 * 16 + 8) = o1;
      }
    }
    __syncthreads();

    #pragma unroll 2
    for (int itL = 0; itL < WHALF / 32; ++itL) {
      const int jo = w * WHALF + itL * 32;
      const h16x8 e1 = *(const h16x8*)(e1p_ + jo);
      const h16x8 e3 = *(const h16x8*)(e3p_ + jo);
      const h16x8 sv = *(const h16x8*)(scp_ + jo);
      const h16x8 md = *(const h16x8*)(&mlds[0][mr][itL * 32 + grp * 8]);
      const h16x8 ms = *(const h16x8*)(&mlds[1][mr][itL * 32 + grp * 8]);

      const h16x8 q = __builtin_elementwise_max(e1 * af8, e3 * bf8);
      const h16x8 eD = q * md;
      const h16x8 eS = q * ms;

      accD = __builtin_amdgcn_mfma_f32_16x16x32_f16(eD, sv, accD, 0, 0, 0);
      accS = __builtin_amdgcn_mfma_f32_16x16x32_f16(eS, sv, accS, 0, 0, 0);
      dnD  = __builtin_amdgcn_mfma_f32_16x16x32_f16(eD, ones, dnD, 0, 0, 0);
      dnS  = __builtin_amdgcn_mfma_f32_16x16x32_f16(eS, ones, dnS, 0, 0, 0);
    }
  }

  // partials: pn[((c*256+t)*8+h)*2+g][row][col], pd[((c*256+t)*8+h)*2+g][row]
  float* pnb = pn + ((((size_t)c * 256 + t) * 8 + h) * 2) * 256;
  #pragma unroll
  for (int r = 0; r < 4; ++r) {
    const int row = grp * 4 + r;
    pnb[row * 16 + mr]       = accD[r];
    pnb[256 + row * 16 + mr] = accS[r];
  }
  if (mr == 0) {
    float* pdb = pd + ((((size_t)c * 256 + t) * 8 + h) * 2) * 16;
    #pragma unroll
    for (int r = 0; r < 4; ++r) {
      pdb[grp * 4 + r]      = dnD[r];
      pdb[16 + grp * 4 + r] = dnS[r];
    }
  }
}

// ---- K3: reduce partials, normalize, output GEMM. grid 256 x 512 ----
__global__ __launch_bounds__(512) void k_reduce(
    const float* __restrict__ pn, const float* __restrict__ pd,
    const unsigned short* __restrict__ Xb, const unsigned short* __restrict__ WpT,
    const float* __restrict__ bsum, float* __restrict__ out)
{
  __shared__ unsigned short catT[16][520];  // [row][ S(128) | D(128) | X(256) ]
  const int t = blockIdx.x, i0 = t * 16;
  const int tid = threadIdx.x;
  {  // stage X rows -> catT cols 256..511
    const int r = tid >> 5, x0 = (tid & 31) * 8;
    *(bf16x8*)(&catT[r][256 + x0]) = *(const bf16x8*)(Xb + (size_t)(i0 + r) * 256 + x0);
  }
  const int h = tid >> 6, lane = tid & 63;
  const int mr = lane & 15, grp = lane >> 4;

  #pragma unroll
  for (int r = 0; r < 4; ++r) {
    const int row = grp * 4 + r;
    float vD = 0.f, vS = 0.f, dD = 0.f, dS = 0.f;
    #pragma unroll
    for (int c = 0; c < NS; ++c) {
      const size_t nb = ((((size_t)c * 256 + t) * 8 + h) * 2) * 256;
      const size_t db = ((((size_t)c * 256 + t) * 8 + h) * 2) * 16;
      vD += pn[nb + row * 16 + mr];
      vS += pn[nb + 256 + row * 16 + mr];
      dD += pd[db + row];
      dS += pd[db + 16 + row];
    }
    const float oS = vS * __builtin_amdgcn_rcpf(fmaxf(dS, 1e-30f));
    const float oD = vD * __builtin_amdgcn_rcpf(fmaxf(dD, 1e-30f));
    catT[row][h * 16 + mr]       = f2bf_rn(oS);
    catT[row][128 + h * 16 + mr] = f2bf_rn(oD);
  }
  __syncthreads();

  // phase B: out[16][128] = catT[16][512] @ W'[512][128] + bsum
  f32x4 o = {0.f, 0.f, 0.f, 0.f};
  const unsigned short* wp = WpT + (size_t)(h * 16 + mr) * 512;
  #pragma unroll
  for (int ks = 0; ks < 16; ++ks) {
    bf16x8 a = *(const bf16x8*)(&catT[mr][ks * 32 + grp * 8]);
    bf16x8 b = *(const bf16x8*)(wp + ks * 32 + grp * 8);
    o = __builtin_amdgcn_mfma_f32_16x16x32_bf16(a, b, o, 0, 0, 0);
  }
  const float bs = bsum[h * 16 + mr];
  #pragma unroll
  for (int r = 0; r < 4; ++r)
    out[(size_t)(i0 + grp * 4 + r) * 128 + h * 16 + mr] = o[r] + bs;
}

extern "C" void kernel_launch(void* const* d_in, const int* in_sizes, int n_in,
                              void* d_out, int out_size, void* d_ws, size_t ws_size,
                              hipStream_t stream) {
  const float* X    = (const float*)d_in[0];
  const float* Dg   = (const float*)d_in[1];
  const float* Sg   = (const float*)d_in[2];
  const float* Ww   = (const float*)d_in[3];
  const float* Wb   = (const float*)d_in[4];
  const float* wu   = (const float*)d_in[5];
  const float* wv   = (const float*)d_in[6];
  const float* Wcat = (const float*)d_in[7];
  const float* Wcb  = (const float*)d_in[8];
  const float* bias = (const float*)d_in[9];
  const float* proj = (const float*)d_in[10];
  const float* prb  = (const float*)d_in[11];
  float* out = (float*)d_out;

  char* ws = (char*)d_ws;
  unsigned short* Xb   = (unsigned short*)(ws);              // 2 MB
  unsigned short* scT  = (unsigned short*)(ws + 0x200000);   // 1 MB (f16)
  float*          f2   = (float*)(ws + 0x300000);            // 128 KB
  unsigned short* E1p  = (unsigned short*)(ws + 0x320000);   // 64 KB (f16)
  unsigned short* E3p  = (unsigned short*)(ws + 0x330000);   // 64 KB (f16)
  unsigned short* WwT  = (unsigned short*)(ws + 0x340000);   // 64 KB
  unsigned short* WpT  = (unsigned short*)(ws + 0x350000);   // 128 KB
  float*          bsum = (float*)(ws + 0x370000);            // 512 B
  float*          pn   = (float*)(ws + 0x780000);            // 8 MB
  float*          pd   = (float*)(ws + 0x1780000);           // 1 MB

  k_prep<<<dim3(512), dim3(256), 0, stream>>>(X, Ww, Wcat, proj, Wcb, bias, prb,
                                              Xb, WwT, WpT, bsum);
  k_score<<<dim3(256), dim3(512), 0, stream>>>(Xb, WwT, Wb, wu, wv, scT, f2, E1p, E3p);
  k_attn<<<dim3(NS * 256), dim3(512), 0, stream>>>(Dg, Sg, scT, E1p, E3p, f2, pn, pd);
  k_reduce<<<dim3(256), dim3(512), 0, stream>>>(pn, pd, Xb, WpT, bsum, out);
}

// Round 10
// 80.852 us; speedup vs baseline: 1.1944x; 1.1944x over previous
//
#include <hip/hip_runtime.h>
#include <hip/hip_bf16.h>

// GAT MultiHeads, MI355X. N=4096, F_IN=256, H=8, D=16, HD=128.
// All inputs/outputs f32; attention inner loop packed f16, masks streamed
// HBM -> LDS via double-buffered global_load_lds (async, one barrier/window).
//
// Math identities (vs reference):
//  - logits[h,i,j] = f1[h,j] + f2[h,i]  (rank-1, never materialized)
//  - exp(lrelu(x)) = max(e^x, e^{0.3x})  (exp monotone, lrelu = max(x,0.3x))
//    => q = max(E1[j]*A[i], E3[j]*B[i]); E1=e^f1, E3=e^{0.3f1}, A=e^f2, B=e^{0.3f2}
//  - no max-subtraction: logits bounded (|x| < ~2), softmax ratio invariant
//  - g in {0,1} => exact in f16; mask applied as packed-f16 multiply
//  - denominators = P @ ones via MFMA (idle pipe), lane gets its row sum
//  - fully-masked rows: denom clamp 1e-30 => output row 0 (matches densify)
//
// LDS swizzle (rule: both-sides-or-neither with global_load_lds):
//  LDS dest linear; SOURCE lane permuted lane^(row&7) (16B units);
//  reads XOR byte offset with ((row&7)<<4). Breaks 16-row same-bank pattern.

#define NN 4096
#define LOG2E 1.44269504088896340736f
#define NS 4          // j-split chunks
#define CHUNK 1024    // NN/NS
#define WCOLS 256     // mask window columns (f32)

typedef short bf16x8 __attribute__((ext_vector_type(8)));
typedef float f32x4  __attribute__((ext_vector_type(4)));
typedef _Float16 h16x8 __attribute__((ext_vector_type(8)));
typedef __fp16  fp16x2 __attribute__((ext_vector_type(2)));

union hu8 { unsigned int u[4]; h16x8 v; };

__device__ __forceinline__ unsigned short f2bf_rn(float f) {
  union { float f; unsigned int i; } v; v.f = f;
  unsigned int r = v.i + 0x7FFFu + ((v.i >> 16) & 1u);  // RTNE
  return (unsigned short)(r >> 16);
}
// two f32 -> packed 2x f16 (RTZ) as u32
__device__ __forceinline__ unsigned int pk2(float lo, float hi) {
  fp16x2 h = __builtin_amdgcn_cvt_pkrtz(lo, hi);
  union { fp16x2 h; unsigned int u; } v; v.h = h; return v.u;
}
// async global->LDS, 16 B per lane; lds dest = base + lane*16 (wave-uniform base)
__device__ __forceinline__ void gload_lds16(const float* src, float* lds) {
  auto g = (const __attribute__((address_space(1))) void*)((unsigned long long)src);
  auto l = (__attribute__((address_space(3))) void*)
               ((unsigned int)(unsigned long long)lds);
  __builtin_amdgcn_global_load_lds(g, l, 16, 0, 0);
}

// ---- K0: one-time conversions. grid 512x256 ----
__global__ __launch_bounds__(256) void k_prep(
    const float* __restrict__ X, const float* __restrict__ Ww,
    const float* __restrict__ Wcat, const float* __restrict__ proj,
    const float* __restrict__ Wcb, const float* __restrict__ bias,
    const float* __restrict__ prb,
    unsigned short* __restrict__ Xb, unsigned short* __restrict__ WwT,
    unsigned short* __restrict__ WpT, float* __restrict__ bsum)
{
  const int tid = blockIdx.x * 256 + threadIdx.x;  // 0..131071
  {  // X[4096][256] f32 -> bf16 (RTNE), 8 elements/thread
    const float4 a = *(const float4*)(X + (size_t)tid * 8);
    const float4 b = *(const float4*)(X + (size_t)tid * 8 + 4);
    uint4 o;
    o.x = (unsigned)f2bf_rn(a.x) | ((unsigned)f2bf_rn(a.y) << 16);
    o.y = (unsigned)f2bf_rn(a.z) | ((unsigned)f2bf_rn(a.w) << 16);
    o.z = (unsigned)f2bf_rn(b.x) | ((unsigned)f2bf_rn(b.y) << 16);
    o.w = (unsigned)f2bf_rn(b.z) | ((unsigned)f2bf_rn(b.w) << 16);
    *(uint4*)(Xb + (size_t)tid * 8) = o;
  }
  if (tid < 32768) {  // WwT[c][k] = Ww[k][c], bf16
    int c = tid & 127, k = tid >> 7;
    WwT[c * 256 + k] = f2bf_rn(Ww[k * 128 + c]);
  }
  if (tid < 65536) {  // WpT[c][k]: k<256 -> Wcat[k][c], else proj[k-256][c]
    int c = tid & 127, k = tid >> 7;
    float v = (k < 256) ? Wcat[k * 128 + c] : proj[(k - 256) * 128 + c];
    WpT[c * 512 + k] = f2bf_rn(v);
  }
  if (tid < 128) bsum[tid] = Wcb[tid] + bias[tid] + prb[tid];
}

// ---- K1: score GEMM + f2 + f16 exp tables. grid 256 x 512 ----
__global__ __launch_bounds__(512) void k_score(
    const unsigned short* __restrict__ Xb, const unsigned short* __restrict__ WwT,
    const float* __restrict__ Wb, const float* __restrict__ wu,
    const float* __restrict__ wv,
    unsigned short* __restrict__ scT, float* __restrict__ f2,
    unsigned short* __restrict__ E1p, unsigned short* __restrict__ E3p)
{
  const int n0 = blockIdx.x * 16;
  const int h = threadIdx.x >> 6, lane = threadIdx.x & 63;
  const int mr = lane & 15, grp = lane >> 4;
  const unsigned short* ap  = Xb  + (size_t)(n0 + mr) * 256;
  const unsigned short* bpp = WwT + (size_t)(h * 16 + mr) * 256;
  f32x4 acc = {0.f, 0.f, 0.f, 0.f};
  #pragma unroll
  for (int ks = 0; ks < 8; ++ks) {
    bf16x8 a = *(const bf16x8*)(ap  + ks * 32 + grp * 8);
    bf16x8 b = *(const bf16x8*)(bpp + ks * 32 + grp * 8);
    acc = __builtin_amdgcn_mfma_f32_16x16x32_bf16(a, b, acc, 0, 0, 0);
  }
  const float wb = Wb[h * 16 + mr];
  float sc[4];
  #pragma unroll
  for (int r = 0; r < 4; ++r) sc[r] = acc[r] + wb;  // score[n0+grp*4+r][h*16+mr]

  {  // scT[h*16+mr][n0+grp*4 .. +3] f16
    uint2 st;
    st.x = pk2(sc[0], sc[1]);
    st.y = pk2(sc[2], sc[3]);
    *(uint2*)(scT + (size_t)(h * 16 + mr) * NN + n0 + grp * 4) = st;
  }

  const float uw = wu[h * 16 + mr], vw = wv[h * 16 + mr];
  float t1[4], t2[4];
  #pragma unroll
  for (int r = 0; r < 4; ++r) { t1[r] = sc[r] * uw; t2[r] = sc[r] * vw; }
  #pragma unroll
  for (int m = 1; m < 16; m <<= 1) {
    #pragma unroll
    for (int r = 0; r < 4; ++r) {
      t1[r] += __shfl_xor(t1[r], m, 64);
      t2[r] += __shfl_xor(t2[r], m, 64);
    }
  }
  if (mr == 0) {
    *(float4*)(f2 + h * NN + n0 + grp * 4) = make_float4(t2[0], t2[1], t2[2], t2[3]);
    float e1[4], e3[4];
    #pragma unroll
    for (int r = 0; r < 4; ++r) {
      e1[r] = __builtin_amdgcn_exp2f(t1[r] * LOG2E);
      e3[r] = __builtin_amdgcn_exp2f(0.3f * t1[r] * LOG2E);
    }
    uint2 p1, p3;
    p1.x = pk2(e1[0], e1[1]);
    p1.y = pk2(e1[2], e1[3]);
    p3.x = pk2(e3[0], e3[1]);
    p3.y = pk2(e3[2], e3[3]);
    *(uint2*)(E1p + h * NN + n0 + grp * 4) = p1;
    *(uint2*)(E3p + h * NN + n0 + grp * 4) = p3;
  }
}

// ---- K2: dual-graph masked softmax attention, j-split x NS ----
// grid = NS*256 (bx = chunk*256 + tile), 512 thr (8 waves = 8 heads).
// Masks streamed once chip-wide via double-buffered global_load_lds windows
// (issue w+1 after barrier, compute w under the in-flight loads).
__global__ __launch_bounds__(512, 4) void k_attn(
    const float* __restrict__ Dg, const float* __restrict__ Sg,
    const unsigned short* __restrict__ scT, const unsigned short* __restrict__ E1p,
    const unsigned short* __restrict__ E3p, const float* __restrict__ f2,
    float* __restrict__ pn, float* __restrict__ pd)
{
  __shared__ float mwin[2][2][16][WCOLS];  // [buf][graph][row][col] linear, 64 KB
  const int bx = blockIdx.x;
  const int c = bx >> 8, t = bx & 255;
  const int i0 = t << 4, j0 = c * CHUNK;
  const int h = threadIdx.x >> 6, lane = threadIdx.x & 63;
  const int mr = lane & 15, grp = lane >> 4;
  const int r7s = (mr & 7) << 2;  // read-side XOR swizzle, f32 units

  const float f2v = f2[h * NN + i0 + mr];
  const _Float16 afh = (_Float16)__builtin_amdgcn_exp2f(f2v * LOG2E);
  const _Float16 bfh = (_Float16)__builtin_amdgcn_exp2f(0.3f * f2v * LOG2E);
  const h16x8 af8 = {afh, afh, afh, afh, afh, afh, afh, afh};
  const h16x8 bf8 = {bfh, bfh, bfh, bfh, bfh, bfh, bfh, bfh};
  const _Float16 one = (_Float16)1.f;
  const h16x8 ones = {one, one, one, one, one, one, one, one};

  const _Float16* e1p_ = (const _Float16*)E1p + h * NN + j0 + grp * 8;
  const _Float16* e3p_ = (const _Float16*)E3p + h * NN + j0 + grp * 8;
  const _Float16* scp_ = (const _Float16*)scT + (size_t)(h * 16 + mr) * NN + j0 + grp * 8;

  f32x4 accD = {0.f,0.f,0.f,0.f}, accS = {0.f,0.f,0.f,0.f};
  f32x4 dnD  = {0.f,0.f,0.f,0.f}, dnS  = {0.f,0.f,0.f,0.f};

  // staging: wave h issues 4 row-chunks (1 KB each) per window.
  // LDS linear; source lane index XOR'd with (row&7) (16B units).
  const int ch0 = h * 4;
  auto ISSUE = [&](int w, int buf) {
    #pragma unroll
    for (int i = 0; i < 4; ++i) {
      const int ch = ch0 + i;
      const int g = ch >> 4, row = ch & 15;
      const float* src = (g ? Sg : Dg) + (size_t)(i0 + row) * NN + j0 + w * WCOLS
                         + ((lane ^ (row & 7)) << 2);
      gload_lds16(src, &mwin[buf][g][row][0]);
    }
  };

  ISSUE(0, 0);
  for (int w = 0; w < CHUNK / WCOLS; ++w) {
    __syncthreads();  // compiler drains vmcnt here: window w ready, prev reads done
    if (w + 1 < CHUNK / WCOLS) ISSUE(w + 1, (w + 1) & 1);
    const float* mb = &mwin[w & 1][0][0][0];
    #pragma unroll
    for (int it8 = 0; it8 < 8; ++it8) {
      const int it = w * 8 + it8;
      const h16x8 e1 = *(const h16x8*)(e1p_ + it * 32);
      const h16x8 e3 = *(const h16x8*)(e3p_ + it * 32);
      const h16x8 sv = *(const h16x8*)(scp_ + it * 32);
      const int lo = it8 * 32 + grp * 8;
      const int pA = mr * WCOLS + (lo ^ r7s);
      const int pB = mr * WCOLS + ((lo + 4) ^ r7s);
      const f32x4 d0 = *(const f32x4*)(mb + pA);
      const f32x4 d1 = *(const f32x4*)(mb + pB);
      const f32x4 s0 = *(const f32x4*)(mb + 4096 + pA);
      const f32x4 s1 = *(const f32x4*)(mb + 4096 + pB);

      hu8 Q, MD, MS;
      Q.v = __builtin_elementwise_max(e1 * af8, e3 * bf8);
      MD.u[0] = pk2(d0.x, d0.y); MD.u[1] = pk2(d0.z, d0.w);
      MD.u[2] = pk2(d1.x, d1.y); MD.u[3] = pk2(d1.z, d1.w);
      MS.u[0] = pk2(s0.x, s0.y); MS.u[1] = pk2(s0.z, s0.w);
      MS.u[2] = pk2(s1.x, s1.y); MS.u[3] = pk2(s1.z, s1.w);
      const h16x8 eD = Q.v * MD.v;
      const h16x8 eS = Q.v * MS.v;

      accD = __builtin_amdgcn_mfma_f32_16x16x32_f16(eD, sv, accD, 0, 0, 0);
      accS = __builtin_amdgcn_mfma_f32_16x16x32_f16(eS, sv, accS, 0, 0, 0);
      dnD  = __builtin_amdgcn_mfma_f32_16x16x32_f16(eD, ones, dnD, 0, 0, 0);
      dnS  = __builtin_amdgcn_mfma_f32_16x16x32_f16(eS, ones, dnS, 0, 0, 0);
    }
  }

  // partials: pn[((c*256+t)*8+h)*2+g][row][col], pd[((c*256+t)*8+h)*2+g][row]
  float* pnb = pn + ((((size_t)c * 256 + t) * 8 + h) * 2) * 256;
  #pragma unroll
  for (int r = 0; r < 4; ++r) {
    const int row = grp * 4 + r;
    pnb[row * 16 + mr]       = accD[r];
    pnb[256 + row * 16 + mr] = accS[r];
  }
  if (mr == 0) {
    float* pdb = pd + ((((size_t)c * 256 + t) * 8 + h) * 2) * 16;
    #pragma unroll
    for (int r = 0; r < 4; ++r) {
      pdb[grp * 4 + r]      = dnD[r];
      pdb[16 + grp * 4 + r] = dnS[r];
    }
  }
}

// ---- K3: reduce partials, normalize, output GEMM. grid 256 x 512 ----
__global__ __launch_bounds__(512) void k_reduce(
    const float* __restrict__ pn, const float* __restrict__ pd,
    const unsigned short* __restrict__ Xb, const unsigned short* __restrict__ WpT,
    const float* __restrict__ bsum, float* __restrict__ out)
{
  __shared__ unsigned short catT[16][520];  // [row][ S(128) | D(128) | X(256) ]
  const int t = blockIdx.x, i0 = t * 16;
  const int tid = threadIdx.x;
  {  // stage X rows -> catT cols 256..511
    const int r = tid >> 5, x0 = (tid & 31) * 8;
    *(bf16x8*)(&catT[r][256 + x0]) = *(const bf16x8*)(Xb + (size_t)(i0 + r) * 256 + x0);
  }
  const int h = tid >> 6, lane = tid & 63;
  const int mr = lane & 15, grp = lane >> 4;

  #pragma unroll
  for (int r = 0; r < 4; ++r) {
    const int row = grp * 4 + r;
    float vD = 0.f, vS = 0.f, dD = 0.f, dS = 0.f;
    #pragma unroll
    for (int c = 0; c < NS; ++c) {
      const size_t nb = ((((size_t)c * 256 + t) * 8 + h) * 2) * 256;
      const size_t db = ((((size_t)c * 256 + t) * 8 + h) * 2) * 16;
      vD += pn[nb + row * 16 + mr];
      vS += pn[nb + 256 + row * 16 + mr];
      dD += pd[db + row];
      dS += pd[db + 16 + row];
    }
    const float oS = vS * __builtin_amdgcn_rcpf(fmaxf(dS, 1e-30f));
    const float oD = vD * __builtin_amdgcn_rcpf(fmaxf(dD, 1e-30f));
    catT[row][h * 16 + mr]       = f2bf_rn(oS);
    catT[row][128 + h * 16 + mr] = f2bf_rn(oD);
  }
  __syncthreads();

  // phase B: out[16][128] = catT[16][512] @ W'[512][128] + bsum
  f32x4 o = {0.f, 0.f, 0.f, 0.f};
  const unsigned short* wp = WpT + (size_t)(h * 16 + mr) * 512;
  #pragma unroll
  for (int ks = 0; ks < 16; ++ks) {
    bf16x8 a = *(const bf16x8*)(&catT[mr][ks * 32 + grp * 8]);
    bf16x8 b = *(const bf16x8*)(wp + ks * 32 + grp * 8);
    o = __builtin_amdgcn_mfma_f32_16x16x32_bf16(a, b, o, 0, 0, 0);
  }
  const float bs = bsum[h * 16 + mr];
  #pragma unroll
  for (int r = 0; r < 4; ++r)
    out[(size_t)(i0 + grp * 4 + r) * 128 + h * 16 + mr] = o[r] + bs;
}

extern "C" void kernel_launch(void* const* d_in, const int* in_sizes, int n_in,
                              void* d_out, int out_size, void* d_ws, size_t ws_size,
                              hipStream_t stream) {
  const float* X    = (const float*)d_in[0];
  const float* Dg   = (const float*)d_in[1];
  const float* Sg   = (const float*)d_in[2];
  const float* Ww   = (const float*)d_in[3];
  const float* Wb   = (const float*)d_in[4];
  const float* wu   = (const float*)d_in[5];
  const float* wv   = (const float*)d_in[6];
  const float* Wcat = (const float*)d_in[7];
  const float* Wcb  = (const float*)d_in[8];
  const float* bias = (const float*)d_in[9];
  const float* proj = (const float*)d_in[10];
  const float* prb  = (const float*)d_in[11];
  float* out = (float*)d_out;

  char* ws = (char*)d_ws;
  unsigned short* Xb   = (unsigned short*)(ws);              // 2 MB
  unsigned short* scT  = (unsigned short*)(ws + 0x200000);   // 1 MB (f16)
  float*          f2   = (float*)(ws + 0x300000);            // 128 KB
  unsigned short* E1p  = (unsigned short*)(ws + 0x320000);   // 64 KB (f16)
  unsigned short* E3p  = (unsigned short*)(ws + 0x330000);   // 64 KB (f16)
  unsigned short* WwT  = (unsigned short*)(ws + 0x340000);   // 64 KB
  unsigned short* WpT  = (unsigned short*)(ws + 0x350000);   // 128 KB
  float*          bsum = (float*)(ws + 0x370000);            // 512 B
  float*          pn   = (float*)(ws + 0x780000);            // 16 MB
  float*          pd   = (float*)(ws + 0x1780000);           // 1 MB

  k_prep<<<dim3(512), dim3(256), 0, stream>>>(X, Ww, Wcat, proj, Wcb, bias, prb,
                                              Xb, WwT, WpT, bsum);
  k_score<<<dim3(256), dim3(512), 0, stream>>>(Xb, WwT, Wb, wu, wv, scT, f2, E1p, E3p);
  k_attn<<<dim3(NS * 256), dim3(512), 0, stream>>>(Dg, Sg, scT, E1p, E3p, f2, pn, pd);
  k_reduce<<<dim3(256), dim3(512), 0, stream>>>(pn, pd, Xb, WpT, bsum, out);
}